// Round 1
// baseline (102.123 us; speedup 1.0000x reference)
//
#include <hip/hip_runtime.h>

// Quanvolution classifier, round 3: fused sim+head.
//
// Algebra (validated in prior rounds): variational circuit is data-independent
// => U (16x16 complex) fixed. Encoder state is a real product state
// s = p (x) q, p,q in R^4.
//   e_w = s^T M_w s,  M_w = Re(U^dag Z_w U)  (real symmetric 16x16)
// Fold pair symmetry:  e_w = sum_{a,b in 10} C_w[a][b] P_a Q_b
// where P_a = p_{j1}p_{j2} over unique pairs (j1<=j2), same for Q.
// => per patch: 4 sincos + ~24 mul + 440 FMA, C (400 floats) read at
// wave-uniform addresses -> scalar (SGPR) loads, no spill.
//
// Round-3 change: one block per image fuses patch simulation with the
// linear head + log_softmax, removing the 25.6 MB feats round-trip and
// one kernel dispatch.
//
// Wire convention (validated in round 1): wire 0 = MSB; i = 4*jp + jq,
// s[i] = p[jp]*q[jq], p = (c0c1, c0s1, s0c1, s0s1), q = (c2c3, c2s3, s2c3, s2s3).

#define NPATCH 196

// ---------------- kernel 1: vparams -> U -> M_w -> C (400 floats) --------
__global__ void qc_build_C(const float* __restrict__ vp,
                           float* __restrict__ Cout) {
  __shared__ float Ur[16][16];   // [i][j]
  __shared__ float Ui[16][16];
  __shared__ float M[4][16][16];
  int t = threadIdx.x;

  if (t < 16) {
    // evolve basis column t through the 3 variational layers
    float sr[16], si[16];
#pragma unroll
    for (int i = 0; i < 16; ++i) { sr[i] = 0.f; si[i] = 0.f; }
    sr[t] = 1.f;

    for (int l = 0; l < 3; ++l) {
#pragma unroll
      for (int w = 0; w < 4; ++w) {
        float thy = vp[l * 8 + (w % 8)];
        float thz = vp[l * 8 + ((w + 1) % 8)];
        float cy, sy, cz, sz;
        __sincosf(0.5f * thy, &sy, &cy);
        __sincosf(0.5f * thz, &sz, &cz);
        const int bit = 8 >> w;
        // RY
#pragma unroll
        for (int i = 0; i < 16; ++i) {
          if (!(i & bit)) {
            int i1 = i | bit;
            float a0r = sr[i], a0i = si[i], a1r = sr[i1], a1i = si[i1];
            sr[i]  = cy * a0r - sy * a1r;  si[i]  = cy * a0i - sy * a1i;
            sr[i1] = sy * a0r + cy * a1r;  si[i1] = sy * a0i + cy * a1i;
          }
        }
        // RZ: amp0 *= e^{-i thz/2}, amp1 *= e^{+i thz/2}
#pragma unroll
        for (int i = 0; i < 16; ++i) {
          float r = sr[i], m = si[i];
          if (i & bit) { sr[i] = r * cz - m * sz; si[i] = m * cz + r * sz; }
          else         { sr[i] = r * cz + m * sz; si[i] = m * cz - r * sz; }
        }
      }
      // CX ring
#pragma unroll
      for (int w = 0; w < 4; ++w) {
        const int cbit = 8 >> w;
        const int tbit = 8 >> ((w + 1) & 3);
#pragma unroll
        for (int i = 0; i < 16; ++i) {
          if ((i & cbit) && !(i & tbit)) {
            int i1 = i | tbit;
            float tr = sr[i], ti = si[i];
            sr[i] = sr[i1]; si[i] = si[i1];
            sr[i1] = tr;    si[i1] = ti;
          }
        }
      }
    }
#pragma unroll
    for (int i = 0; i < 16; ++i) { Ur[i][t] = sr[i]; Ui[i][t] = si[i]; }
  }
  __syncthreads();

  // M_w[r][c] = sum_i sgn_w(i) * (Ur[i][r]Ur[i][c] + Ui[i][r]Ui[i][c])
  for (int e = t; e < 1024; e += 64) {
    int w = e >> 8, r = (e >> 4) & 15, c = e & 15;
    float acc = 0.f;
#pragma unroll
    for (int i = 0; i < 16; ++i) {
      float sgn = ((i >> (3 - w)) & 1) ? -1.f : 1.f;
      acc += sgn * (Ur[i][r] * Ur[i][c] + Ui[i][r] * Ui[i][c]);
    }
    M[w][r][c] = acc;
  }
  __syncthreads();

  // C_w[a][b] = sum over distinct orderings of pair a (rows) x pair b (cols)
  const int pj1[10] = {0, 0, 0, 0, 1, 1, 1, 2, 2, 3};
  const int pj2[10] = {0, 1, 2, 3, 1, 2, 3, 2, 3, 3};
  for (int e = t; e < 400; e += 64) {
    int w = e / 100;
    int rem = e - w * 100;
    int a = rem / 10;
    int bq = rem - a * 10;
    int j1 = pj1[a], j2 = pj2[a], k1 = pj1[bq], k2 = pj2[bq];
    float v = M[w][4 * j1 + k1][4 * j2 + k2];
    if (k1 != k2) v += M[w][4 * j1 + k2][4 * j2 + k1];
    if (j1 != j2) {
      v += M[w][4 * j2 + k1][4 * j1 + k2];
      if (k1 != k2) v += M[w][4 * j2 + k2][4 * j1 + k1];
    }
    Cout[e] = v;
  }
}

// ---------------- kernel 2 (fused): per-image patches -> logits ----------
// One block = one image. Thread t < 196 owns patch t. The image (3136 B)
// is staged through LDS with one coalesced float4 burst; per-patch
// expectation values feed the head dot-product immediately (W rows are
// L2-resident), then a shuffle+LDS block reduction produces the 10 logits.
__global__ __launch_bounds__(256) void qc_fused(const float* __restrict__ x,
                                                const float* __restrict__ C,
                                                const float4* __restrict__ W4,
                                                const float* __restrict__ bias,
                                                float* __restrict__ out) {
  __shared__ float img[784];
  __shared__ float red[4][10];

  const int b = blockIdx.x;
  const int t = threadIdx.x;
  const float* xb = x + (size_t)b * 784;

  if (t < NPATCH) {
    ((float4*)img)[t] = ((const float4*)xb)[t];  // 196*16B = whole image
  }
  __syncthreads();

  float lg[10];
#pragma unroll
  for (int c = 0; c < 10; ++c) lg[c] = 0.f;

  if (t < NPATCH) {
    const int pr = t / 14;
    const int pc = t - pr * 14;
    float2 top = *(const float2*)(img + (2 * pr) * 28 + 2 * pc);
    float2 bot = *(const float2*)(img + (2 * pr + 1) * 28 + 2 * pc);

    float s0, c0, s1, c1, s2, c2, s3, c3;
    __sincosf(0.5f * top.x, &s0, &c0);
    __sincosf(0.5f * top.y, &s1, &c1);
    __sincosf(0.5f * bot.x, &s2, &c2);
    __sincosf(0.5f * bot.y, &s3, &c3);

    float p0 = c0 * c1, p1 = c0 * s1, p2 = s0 * c1, p3 = s0 * s1;
    float q0 = c2 * c3, q1 = c2 * s3, q2 = s2 * c3, q3 = s2 * s3;

    float P[10] = {p0 * p0, p0 * p1, p0 * p2, p0 * p3, p1 * p1,
                   p1 * p2, p1 * p3, p2 * p2, p2 * p3, p3 * p3};
    float Q[10] = {q0 * q0, q0 * q1, q0 * q2, q0 * q3, q1 * q1,
                   q1 * q2, q1 * q3, q2 * q2, q2 * q3, q3 * q3};

    float e[4];
#pragma unroll
    for (int w = 0; w < 4; ++w) {
      float acc = 0.f;
#pragma unroll
      for (int a = 0; a < 10; ++a) {
        const float* row = C + (w * 10 + a) * 10;
        float tt = row[0] * Q[0] + row[1] * Q[1] + row[2] * Q[2] +
                   row[3] * Q[3] + row[4] * Q[4] + row[5] * Q[5] +
                   row[6] * Q[6] + row[7] * Q[7] + row[8] * Q[8] +
                   row[9] * Q[9];
        acc += P[a] * tt;
      }
      e[w] = acc;
    }

    // head partials: feats[b, t*4 + w] dotted against W[c, t*4 + w]
#pragma unroll
    for (int c = 0; c < 10; ++c) {
      float4 w = W4[c * NPATCH + t];
      lg[c] = e[0] * w.x + e[1] * w.y + e[2] * w.z + e[3] * w.w;
    }
  }

  // wave-level reduction (64 lanes), threads t>=196 contribute zeros
#pragma unroll
  for (int off = 32; off >= 1; off >>= 1)
#pragma unroll
    for (int c = 0; c < 10; ++c)
      lg[c] += __shfl_xor(lg[c], off, 64);

  const int wave = t >> 6;
  const int lane = t & 63;
  if (lane == 0) {
#pragma unroll
    for (int c = 0; c < 10; ++c) red[wave][c] = lg[c];
  }
  __syncthreads();

  if (t == 0) {
    float L[10], m = -1e30f;
#pragma unroll
    for (int c = 0; c < 10; ++c) {
      L[c] = red[0][c] + red[1][c] + red[2][c] + red[3][c] + bias[c];
      m = fmaxf(m, L[c]);
    }
    float ssum = 0.f;
#pragma unroll
    for (int c = 0; c < 10; ++c) ssum += __expf(L[c] - m);
    float ls = m + __logf(ssum);
#pragma unroll
    for (int c = 0; c < 10; ++c) out[b * 10 + c] = L[c] - ls;
  }
}

extern "C" void kernel_launch(void* const* d_in, const int* in_sizes, int n_in,
                              void* d_out, int out_size, void* d_ws, size_t ws_size,
                              hipStream_t stream) {
  const float* x    = (const float*)d_in[0];  // (B,1,28,28)
  const float* vp   = (const float*)d_in[1];  // (3,8)
  const float* W    = (const float*)d_in[2];  // (10,784)
  const float* bias = (const float*)d_in[3];  // (10,)
  float* out = (float*)d_out;

  int B = in_sizes[0] / 784;

  float* Cws = (float*)d_ws;  // 400 floats (1.6 KB)

  qc_build_C<<<1, 64, 0, stream>>>(vp, Cws);
  qc_fused<<<B, 256, 0, stream>>>(x, Cws, (const float4*)W, bias, out);
}

// Round 2
// 95.424 us; speedup vs baseline: 1.0702x; 1.0702x over previous
//
#include <hip/hip_runtime.h>

// Quanvolution classifier, round 4: fused sim+head, packed-f32 core.
//
// Algebra (validated in prior rounds): variational circuit is data-independent
// => U (16x16 complex) fixed. Encoder state is a real product state
// s = p (x) q, p,q in R^4.
//   e_w = s^T M_w s,  M_w = Re(U^dag Z_w U)  (real symmetric 16x16)
// Fold pair symmetry:  e_w = sum_{a,b in 10} C_w[a][b] P_a Q_b
// where P_a = p_{j1}p_{j2} over unique pairs (j1<=j2), same for Q.
//
// Round-4 change: C stored w-fastest (float4 per (a,b) pair) so the inner
// loop is t = P[a]*Q[b]; acc01 += t2*C[ab].xy; acc23 += t2*C[ab].zw —
// lowering to v_pk_fma_f32 (2 FMA/instr). Core: 440 scalar FMA -> ~100 mul
// + 200 pk_fma. C reads remain wave-uniform -> s_load, no LDS, no spill.
//
// Wire convention (validated in round 1): wire 0 = MSB; i = 4*jp + jq,
// s[i] = p[jp]*q[jq], p = (c0c1, c0s1, s0c1, s0s1), q = (c2c3, c2s3, s2c3, s2s3).

#define NPATCH 196

typedef float f2 __attribute__((ext_vector_type(2)));

// ---------------- kernel 1: vparams -> U -> M_w -> C (400 floats) --------
// Layout change: Cout[(a*10+b)*4 + w] = C_w[a][b]  (w fastest, float4/ab)
__global__ void qc_build_C(const float* __restrict__ vp,
                           float* __restrict__ Cout) {
  __shared__ float Ur[16][16];   // [i][j]
  __shared__ float Ui[16][16];
  __shared__ float M[4][16][16];
  int t = threadIdx.x;

  if (t < 16) {
    // evolve basis column t through the 3 variational layers
    float sr[16], si[16];
#pragma unroll
    for (int i = 0; i < 16; ++i) { sr[i] = 0.f; si[i] = 0.f; }
    sr[t] = 1.f;

    for (int l = 0; l < 3; ++l) {
#pragma unroll
      for (int w = 0; w < 4; ++w) {
        float thy = vp[l * 8 + (w % 8)];
        float thz = vp[l * 8 + ((w + 1) % 8)];
        float cy, sy, cz, sz;
        __sincosf(0.5f * thy, &sy, &cy);
        __sincosf(0.5f * thz, &sz, &cz);
        const int bit = 8 >> w;
        // RY
#pragma unroll
        for (int i = 0; i < 16; ++i) {
          if (!(i & bit)) {
            int i1 = i | bit;
            float a0r = sr[i], a0i = si[i], a1r = sr[i1], a1i = si[i1];
            sr[i]  = cy * a0r - sy * a1r;  si[i]  = cy * a0i - sy * a1i;
            sr[i1] = sy * a0r + cy * a1r;  si[i1] = sy * a0i + cy * a1i;
          }
        }
        // RZ: amp0 *= e^{-i thz/2}, amp1 *= e^{+i thz/2}
#pragma unroll
        for (int i = 0; i < 16; ++i) {
          float r = sr[i], m = si[i];
          if (i & bit) { sr[i] = r * cz - m * sz; si[i] = m * cz + r * sz; }
          else         { sr[i] = r * cz + m * sz; si[i] = m * cz - r * sz; }
        }
      }
      // CX ring
#pragma unroll
      for (int w = 0; w < 4; ++w) {
        const int cbit = 8 >> w;
        const int tbit = 8 >> ((w + 1) & 3);
#pragma unroll
        for (int i = 0; i < 16; ++i) {
          if ((i & cbit) && !(i & tbit)) {
            int i1 = i | tbit;
            float tr = sr[i], ti = si[i];
            sr[i] = sr[i1]; si[i] = si[i1];
            sr[i1] = tr;    si[i1] = ti;
          }
        }
      }
    }
#pragma unroll
    for (int i = 0; i < 16; ++i) { Ur[i][t] = sr[i]; Ui[i][t] = si[i]; }
  }
  __syncthreads();

  // M_w[r][c] = sum_i sgn_w(i) * (Ur[i][r]Ur[i][c] + Ui[i][r]Ui[i][c])
  for (int e = t; e < 1024; e += 64) {
    int w = e >> 8, r = (e >> 4) & 15, c = e & 15;
    float acc = 0.f;
#pragma unroll
    for (int i = 0; i < 16; ++i) {
      float sgn = ((i >> (3 - w)) & 1) ? -1.f : 1.f;
      acc += sgn * (Ur[i][r] * Ur[i][c] + Ui[i][r] * Ui[i][c]);
    }
    M[w][r][c] = acc;
  }
  __syncthreads();

  // C_w[a][b] = sum over distinct orderings of pair a (rows) x pair b (cols)
  const int pj1[10] = {0, 0, 0, 0, 1, 1, 1, 2, 2, 3};
  const int pj2[10] = {0, 1, 2, 3, 1, 2, 3, 2, 3, 3};
  for (int e = t; e < 400; e += 64) {
    int w = e / 100;
    int rem = e - w * 100;          // rem = a*10 + b
    int a = rem / 10;
    int bq = rem - a * 10;
    int j1 = pj1[a], j2 = pj2[a], k1 = pj1[bq], k2 = pj2[bq];
    float v = M[w][4 * j1 + k1][4 * j2 + k2];
    if (k1 != k2) v += M[w][4 * j1 + k2][4 * j2 + k1];
    if (j1 != j2) {
      v += M[w][4 * j2 + k1][4 * j1 + k2];
      if (k1 != k2) v += M[w][4 * j2 + k2][4 * j1 + k1];
    }
    Cout[rem * 4 + w] = v;          // w-fastest layout
  }
}

// ---------------- kernel 2 (fused): per-image patches -> logits ----------
// One block = one image. Thread t < 196 owns patch t.
__global__ __launch_bounds__(256) void qc_fused(const float* __restrict__ x,
                                                const float* __restrict__ C,
                                                const float4* __restrict__ W4,
                                                const float* __restrict__ bias,
                                                float* __restrict__ out) {
  __shared__ float img[784];
  __shared__ float red[4][10];

  const int b = blockIdx.x;
  const int t = threadIdx.x;
  const float* xb = x + (size_t)b * 784;

  if (t < NPATCH) {
    ((float4*)img)[t] = ((const float4*)xb)[t];  // 196*16B = whole image
  }
  __syncthreads();

  float lg[10];
#pragma unroll
  for (int c = 0; c < 10; ++c) lg[c] = 0.f;

  if (t < NPATCH) {
    const int pr = t / 14;
    const int pc = t - pr * 14;
    float2 top = *(const float2*)(img + (2 * pr) * 28 + 2 * pc);
    float2 bot = *(const float2*)(img + (2 * pr + 1) * 28 + 2 * pc);

    float s0, c0, s1, c1, s2, c2, s3, c3;
    __sincosf(0.5f * top.x, &s0, &c0);
    __sincosf(0.5f * top.y, &s1, &c1);
    __sincosf(0.5f * bot.x, &s2, &c2);
    __sincosf(0.5f * bot.y, &s3, &c3);

    float p0 = c0 * c1, p1 = c0 * s1, p2 = s0 * c1, p3 = s0 * s1;
    float q0 = c2 * c3, q1 = c2 * s3, q2 = s2 * c3, q3 = s2 * s3;

    float P[10] = {p0 * p0, p0 * p1, p0 * p2, p0 * p3, p1 * p1,
                   p1 * p2, p1 * p3, p2 * p2, p2 * p3, p3 * p3};
    float Q[10] = {q0 * q0, q0 * q1, q0 * q2, q0 * q3, q1 * q1,
                   q1 * q2, q1 * q3, q2 * q2, q2 * q3, q3 * q3};

    // e_w = sum_ab C_w[ab] P_a Q_b with w-packed C -> v_pk_fma_f32
    f2 acc01 = {0.f, 0.f};
    f2 acc23 = {0.f, 0.f};
    const f2* C2 = (const f2*)C;   // C2[ab*2+0] = (C0,C1), [ab*2+1] = (C2,C3)
#pragma unroll
    for (int a = 0; a < 10; ++a) {
#pragma unroll
      for (int bq = 0; bq < 10; ++bq) {
        const int ab = a * 10 + bq;
        float tv = P[a] * Q[bq];
        f2 t2 = {tv, tv};
        acc01 += t2 * C2[ab * 2 + 0];
        acc23 += t2 * C2[ab * 2 + 1];
      }
    }

    // head partials: e dotted against W[c, t*4 + w]
#pragma unroll
    for (int c = 0; c < 10; ++c) {
      float4 w = W4[c * NPATCH + t];
      lg[c] = acc01.x * w.x + acc01.y * w.y + acc23.x * w.z + acc23.y * w.w;
    }
  }

  // wave-level reduction (64 lanes), threads t>=196 contribute zeros
#pragma unroll
  for (int off = 32; off >= 1; off >>= 1)
#pragma unroll
    for (int c = 0; c < 10; ++c)
      lg[c] += __shfl_xor(lg[c], off, 64);

  const int wave = t >> 6;
  const int lane = t & 63;
  if (lane == 0) {
#pragma unroll
    for (int c = 0; c < 10; ++c) red[wave][c] = lg[c];
  }
  __syncthreads();

  if (t == 0) {
    float L[10], m = -1e30f;
#pragma unroll
    for (int c = 0; c < 10; ++c) {
      L[c] = red[0][c] + red[1][c] + red[2][c] + red[3][c] + bias[c];
      m = fmaxf(m, L[c]);
    }
    float ssum = 0.f;
#pragma unroll
    for (int c = 0; c < 10; ++c) ssum += __expf(L[c] - m);
    float ls = m + __logf(ssum);
#pragma unroll
    for (int c = 0; c < 10; ++c) out[b * 10 + c] = L[c] - ls;
  }
}

extern "C" void kernel_launch(void* const* d_in, const int* in_sizes, int n_in,
                              void* d_out, int out_size, void* d_ws, size_t ws_size,
                              hipStream_t stream) {
  const float* x    = (const float*)d_in[0];  // (B,1,28,28)
  const float* vp   = (const float*)d_in[1];  // (3,8)
  const float* W    = (const float*)d_in[2];  // (10,784)
  const float* bias = (const float*)d_in[3];  // (10,)
  float* out = (float*)d_out;

  int B = in_sizes[0] / 784;

  float* Cws = (float*)d_ws;  // 400 floats (1.6 KB)

  qc_build_C<<<1, 64, 0, stream>>>(vp, Cws);
  qc_fused<<<B, 256, 0, stream>>>(x, Cws, (const float4*)W, bias, out);
}

// Round 3
// 94.310 us; speedup vs baseline: 1.0828x; 1.0118x over previous
//
#include <hip/hip_runtime.h>

// Quanvolution classifier, round 5: fused sim+head, 220-pk core, direct loads.
//
// Algebra (validated in prior rounds): variational circuit is data-independent
// => U (16x16 complex) fixed. Encoder state is a real product state
// s = p (x) q, p,q in R^4.
//   e_w = s^T M_w s,  M_w = Re(U^dag Z_w U)  (real symmetric 16x16)
// Fold pair symmetry:  e_w = sum_{a,b in 10} C_w[a][b] P_a Q_b
// where P_a = p_{j1}p_{j2} over unique pairs (j1<=j2), same for Q.
//
// Round-5 changes (all VALU-count, zero new memory traffic):
//  1. core: e_w = sum_a P_a * (sum_b C_w[a][b] Q_b) -> 220 v_pk_fma_f32
//     (was 100 v_mul + 200 pk_fma). Only +4 VGPRs (per-a fold, no D array).
//  2. head: packed dot (2 pk + 1 add per class, was 4 FMA).
//  3. per-thread direct global loads of the 2x2 patch (x read exactly once,
//     14-lane contiguous runs) -- removes img LDS stage + one barrier.
//
// Wire convention (validated in round 1): wire 0 = MSB; i = 4*jp + jq,
// s[i] = p[jp]*q[jq], p = (c0c1, c0s1, s0c1, s0s1), q = (c2c3, c2s3, s2c3, s2s3).

#define NPATCH 196

typedef float f2 __attribute__((ext_vector_type(2)));

// ---------------- kernel 1: vparams -> U -> M_w -> C (400 floats) --------
// Layout: Cout[(a*10+b)*4 + w] = C_w[a][b]  (w fastest, float4 per (a,b))
__global__ void qc_build_C(const float* __restrict__ vp,
                           float* __restrict__ Cout) {
  __shared__ float Ur[16][16];   // [i][j]
  __shared__ float Ui[16][16];
  __shared__ float M[4][16][16];
  int t = threadIdx.x;

  if (t < 16) {
    // evolve basis column t through the 3 variational layers
    float sr[16], si[16];
#pragma unroll
    for (int i = 0; i < 16; ++i) { sr[i] = 0.f; si[i] = 0.f; }
    sr[t] = 1.f;

    for (int l = 0; l < 3; ++l) {
#pragma unroll
      for (int w = 0; w < 4; ++w) {
        float thy = vp[l * 8 + (w % 8)];
        float thz = vp[l * 8 + ((w + 1) % 8)];
        float cy, sy, cz, sz;
        __sincosf(0.5f * thy, &sy, &cy);
        __sincosf(0.5f * thz, &sz, &cz);
        const int bit = 8 >> w;
        // RY
#pragma unroll
        for (int i = 0; i < 16; ++i) {
          if (!(i & bit)) {
            int i1 = i | bit;
            float a0r = sr[i], a0i = si[i], a1r = sr[i1], a1i = si[i1];
            sr[i]  = cy * a0r - sy * a1r;  si[i]  = cy * a0i - sy * a1i;
            sr[i1] = sy * a0r + cy * a1r;  si[i1] = sy * a0i + cy * a1i;
          }
        }
        // RZ: amp0 *= e^{-i thz/2}, amp1 *= e^{+i thz/2}
#pragma unroll
        for (int i = 0; i < 16; ++i) {
          float r = sr[i], m = si[i];
          if (i & bit) { sr[i] = r * cz - m * sz; si[i] = m * cz + r * sz; }
          else         { sr[i] = r * cz + m * sz; si[i] = m * cz - r * sz; }
        }
      }
      // CX ring
#pragma unroll
      for (int w = 0; w < 4; ++w) {
        const int cbit = 8 >> w;
        const int tbit = 8 >> ((w + 1) & 3);
#pragma unroll
        for (int i = 0; i < 16; ++i) {
          if ((i & cbit) && !(i & tbit)) {
            int i1 = i | tbit;
            float tr = sr[i], ti = si[i];
            sr[i] = sr[i1]; si[i] = si[i1];
            sr[i1] = tr;    si[i1] = ti;
          }
        }
      }
    }
#pragma unroll
    for (int i = 0; i < 16; ++i) { Ur[i][t] = sr[i]; Ui[i][t] = si[i]; }
  }
  __syncthreads();

  // M_w[r][c] = sum_i sgn_w(i) * (Ur[i][r]Ur[i][c] + Ui[i][r]Ui[i][c])
  for (int e = t; e < 1024; e += 64) {
    int w = e >> 8, r = (e >> 4) & 15, c = e & 15;
    float acc = 0.f;
#pragma unroll
    for (int i = 0; i < 16; ++i) {
      float sgn = ((i >> (3 - w)) & 1) ? -1.f : 1.f;
      acc += sgn * (Ur[i][r] * Ur[i][c] + Ui[i][r] * Ui[i][c]);
    }
    M[w][r][c] = acc;
  }
  __syncthreads();

  // C_w[a][b] = sum over distinct orderings of pair a (rows) x pair b (cols)
  const int pj1[10] = {0, 0, 0, 0, 1, 1, 1, 2, 2, 3};
  const int pj2[10] = {0, 1, 2, 3, 1, 2, 3, 2, 3, 3};
  for (int e = t; e < 400; e += 64) {
    int w = e / 100;
    int rem = e - w * 100;          // rem = a*10 + b
    int a = rem / 10;
    int bq = rem - a * 10;
    int j1 = pj1[a], j2 = pj2[a], k1 = pj1[bq], k2 = pj2[bq];
    float v = M[w][4 * j1 + k1][4 * j2 + k2];
    if (k1 != k2) v += M[w][4 * j1 + k2][4 * j2 + k1];
    if (j1 != j2) {
      v += M[w][4 * j2 + k1][4 * j1 + k2];
      if (k1 != k2) v += M[w][4 * j2 + k2][4 * j1 + k1];
    }
    Cout[rem * 4 + w] = v;          // w-fastest layout
  }
}

// ---------------- kernel 2 (fused): per-image patches -> logits ----------
// One block = one image. Thread t < 196 owns patch t.
__global__ __launch_bounds__(256) void qc_fused(const float* __restrict__ x,
                                                const float* __restrict__ C,
                                                const float4* __restrict__ W4,
                                                const float* __restrict__ bias,
                                                float* __restrict__ out) {
  __shared__ float red[4][10];

  const int b = blockIdx.x;
  const int t = threadIdx.x;

  float lg[10];
#pragma unroll
  for (int c = 0; c < 10; ++c) lg[c] = 0.f;

  if (t < NPATCH) {
    const int pr = t / 14;
    const int pc = t - pr * 14;
    const float* xb = x + (size_t)b * 784;
    float2 top = *(const float2*)(xb + (2 * pr) * 28 + 2 * pc);
    float2 bot = *(const float2*)(xb + (2 * pr + 1) * 28 + 2 * pc);

    float s0, c0, s1, c1, s2, c2, s3, c3;
    __sincosf(0.5f * top.x, &s0, &c0);
    __sincosf(0.5f * top.y, &s1, &c1);
    __sincosf(0.5f * bot.x, &s2, &c2);
    __sincosf(0.5f * bot.y, &s3, &c3);

    float p0 = c0 * c1, p1 = c0 * s1, p2 = s0 * c1, p3 = s0 * s1;
    float q0 = c2 * c3, q1 = c2 * s3, q2 = s2 * c3, q3 = s2 * s3;

    float P[10] = {p0 * p0, p0 * p1, p0 * p2, p0 * p3, p1 * p1,
                   p1 * p2, p1 * p3, p2 * p2, p2 * p3, p3 * p3};
    float Q[10] = {q0 * q0, q0 * q1, q0 * q2, q0 * q3, q1 * q1,
                   q1 * q2, q1 * q3, q2 * q2, q2 * q3, q3 * q3};

    // e_w = sum_a P[a] * (sum_b C_w[a][b] Q[b])  -- 220 v_pk_fma_f32
    f2 acc01 = {0.f, 0.f};
    f2 acc23 = {0.f, 0.f};
    const f2* C2 = (const f2*)C;   // C2[ab*2+0] = (C0,C1), [ab*2+1] = (C2,C3)
#pragma unroll
    for (int a = 0; a < 10; ++a) {
      f2 r01 = {0.f, 0.f};
      f2 r23 = {0.f, 0.f};
#pragma unroll
      for (int bq = 0; bq < 10; ++bq) {
        const int ab = a * 10 + bq;
        f2 q2 = {Q[bq], Q[bq]};
        r01 += q2 * C2[ab * 2 + 0];
        r23 += q2 * C2[ab * 2 + 1];
      }
      f2 p2 = {P[a], P[a]};
      acc01 += p2 * r01;
      acc23 += p2 * r23;
    }

    // head partials: e dotted against W[c, t*4 + w] (packed)
#pragma unroll
    for (int c = 0; c < 10; ++c) {
      float4 w = W4[c * NPATCH + t];
      f2 w01 = {w.x, w.y};
      f2 w23 = {w.z, w.w};
      f2 h = acc01 * w01 + acc23 * w23;
      lg[c] = h.x + h.y;
    }
  }

  // wave-level reduction (64 lanes), threads t>=196 contribute zeros
#pragma unroll
  for (int off = 32; off >= 1; off >>= 1)
#pragma unroll
    for (int c = 0; c < 10; ++c)
      lg[c] += __shfl_xor(lg[c], off, 64);

  const int wave = t >> 6;
  const int lane = t & 63;
  if (lane == 0) {
#pragma unroll
    for (int c = 0; c < 10; ++c) red[wave][c] = lg[c];
  }
  __syncthreads();

  if (t == 0) {
    float L[10], m = -1e30f;
#pragma unroll
    for (int c = 0; c < 10; ++c) {
      L[c] = red[0][c] + red[1][c] + red[2][c] + red[3][c] + bias[c];
      m = fmaxf(m, L[c]);
    }
    float ssum = 0.f;
#pragma unroll
    for (int c = 0; c < 10; ++c) ssum += __expf(L[c] - m);
    float ls = m + __logf(ssum);
#pragma unroll
    for (int c = 0; c < 10; ++c) out[b * 10 + c] = L[c] - ls;
  }
}

extern "C" void kernel_launch(void* const* d_in, const int* in_sizes, int n_in,
                              void* d_out, int out_size, void* d_ws, size_t ws_size,
                              hipStream_t stream) {
  const float* x    = (const float*)d_in[0];  // (B,1,28,28)
  const float* vp   = (const float*)d_in[1];  // (3,8)
  const float* W    = (const float*)d_in[2];  // (10,784)
  const float* bias = (const float*)d_in[3];  // (10,)
  float* out = (float*)d_out;

  int B = in_sizes[0] / 784;

  float* Cws = (float*)d_ws;  // 400 floats (1.6 KB)

  qc_build_C<<<1, 64, 0, stream>>>(vp, Cws);
  qc_fused<<<B, 256, 0, stream>>>(x, Cws, (const float4*)W, bias, out);
}